// Round 1
// baseline (104.592 us; speedup 1.0000x reference)
//
#include <hip/hip_runtime.h>

// EdgeConv forward, Round 7: algebraic max-factorization.
//
// out_i = max_j relu(W@[x_i; x_j-x_i] + b)
//       = relu( base_i + max_{j in N(i)} y_j )        <- relu/+base monotone
// with y_j = x_j @ W2^T (per-NODE, not per-edge) and
//      base_i = b + x_i @ (W1-W2)^T.
//
// prep_gemm: one dense 50k x 64 x 64 MFMA pass producing y (fp16) and
//            base (fp16) in ws.  0.8 GFLOP total (was 6.5 GFLOP per-edge).
// edge_max:  pure gather kernel. Per node: 16 random 128B fp16 row reads,
//            packed v_pk_max_f16 tree, +base, relu, coalesced f32 store.
//            No MFMA, no W-table, no shfl -> lower VGPR, deeper MLP.
//
// Gather volume unchanged (800k x 128B = 102 MB logical, y = 6.4 MB
// distinct, cache-served). If this kernel doesn't beat ~20us the random
// line service rate is the ceiling.

#define DEG 16
#define C 64
#define WPB 4    // waves per block

typedef __attribute__((ext_vector_type(8))) short s16x8;   // 8 bf16
typedef __attribute__((ext_vector_type(4))) float f32x4;
typedef __attribute__((ext_vector_type(4))) int   i32x4;
typedef _Float16 h8 __attribute__((ext_vector_type(8)));   // 8 fp16 = 16B

__device__ __forceinline__ unsigned short f2bf(float f) {
    union { float f; unsigned u; } v; v.f = f;
    unsigned u = v.u + 0x7FFFu + ((v.u >> 16) & 1u);  // round-nearest-even
    return (unsigned short)(u >> 16);
}

// ---------------------------------------------------------------------------
// prep: y[N][64] fp16 = x @ W2^T ;  base[N][64] fp16 = b + x @ (W1-W2)^T
// 16 nodes per wave via mfma_f32_16x16x32_bf16 (m89/m91-verified layouts):
//   A[m=lane&15][k=quad*8+j],  B[k][n=lane&15],  D: col=lane&15, row=quad*4+reg
// ---------------------------------------------------------------------------
__global__ __launch_bounds__(256) void prep_gemm(
    const float* __restrict__ x, const float* __restrict__ W,
    const float* __restrict__ bias,
    _Float16* __restrict__ y, _Float16* __restrict__ base,
    int n_groups, int n_nodes)
{
    const int lane = threadIdx.x & 63;
    const int wave = threadIdx.x >> 6;
    const int col  = lane & 15;
    const int quad = lane >> 4;
    int g = blockIdx.x * WPB + wave;
    if (g >= n_groups) g = n_groups - 1;   // dup work, identical writes

    // W fragments, built in-wave (W is 32KB, L1/L2-hot)
    s16x8 bd[4][2], b2[4][2];
    #pragma unroll
    for (int nt = 0; nt < 4; ++nt) {
        const float* wrow = W + (size_t)(nt * 16 + col) * (2 * C);
        #pragma unroll
        for (int ks = 0; ks < 2; ++ks) {
            const int k0 = ks * 32 + quad * 8;
            f32x4 w1a = *(const f32x4*)(wrow + k0);
            f32x4 w1b = *(const f32x4*)(wrow + k0 + 4);
            f32x4 w2a = *(const f32x4*)(wrow + C + k0);
            f32x4 w2b = *(const f32x4*)(wrow + C + k0 + 4);
            s16x8 t2, td;
            #pragma unroll
            for (int j = 0; j < 4; ++j) {
                t2[j]     = (short)f2bf(w2a[j]);
                t2[j + 4] = (short)f2bf(w2b[j]);
                td[j]     = (short)f2bf(w1a[j] - w2a[j]);
                td[j + 4] = (short)f2bf(w1b[j] - w2b[j]);
            }
            bd[nt][ks] = td;
            b2[nt][ks] = t2;
        }
    }

    // A fragments: 16 x-rows of this group, converted fp32->bf16 in-lane
    int arow = g * 16 + col;
    if (arow >= n_nodes) arow = n_nodes - 1;
    const float* xr = x + (size_t)arow * C;
    f32x4 xa0 = __builtin_nontemporal_load((const f32x4*)(xr + quad * 8));
    f32x4 xa1 = __builtin_nontemporal_load((const f32x4*)(xr + quad * 8 + 4));
    f32x4 xb0 = __builtin_nontemporal_load((const f32x4*)(xr + 32 + quad * 8));
    f32x4 xb1 = __builtin_nontemporal_load((const f32x4*)(xr + 32 + quad * 8 + 4));
    s16x8 xi0, xi1;
    #pragma unroll
    for (int j = 0; j < 4; ++j) {
        xi0[j]     = (short)f2bf(xa0[j]);
        xi0[j + 4] = (short)f2bf(xa1[j]);
        xi1[j]     = (short)f2bf(xb0[j]);
        xi1[j + 4] = (short)f2bf(xb1[j]);
    }

    f32x4 yD[4], bD[4];
    #pragma unroll
    for (int nt = 0; nt < 4; ++nt) {
        float bv = bias[nt * 16 + col];
        bD[nt] = (f32x4){bv, bv, bv, bv};
        yD[nt] = (f32x4){0.f, 0.f, 0.f, 0.f};
    }
    #pragma unroll
    for (int nt = 0; nt < 4; ++nt) {
        yD[nt] = __builtin_amdgcn_mfma_f32_16x16x32_bf16(xi0, b2[nt][0], yD[nt], 0, 0, 0);
        yD[nt] = __builtin_amdgcn_mfma_f32_16x16x32_bf16(xi1, b2[nt][1], yD[nt], 0, 0, 0);
        bD[nt] = __builtin_amdgcn_mfma_f32_16x16x32_bf16(xi0, bd[nt][0], bD[nt], 0, 0, 0);
        bD[nt] = __builtin_amdgcn_mfma_f32_16x16x32_bf16(xi1, bd[nt][1], bD[nt], 0, 0, 0);
    }

    // fp16 stores; D element (row = quad*4+reg, col = nt*16+col)
    #pragma unroll
    for (int nt = 0; nt < 4; ++nt) {
        #pragma unroll
        for (int reg = 0; reg < 4; ++reg) {
            int orow = g * 16 + quad * 4 + reg;
            if (orow < n_nodes) {
                size_t o = (size_t)orow * C + nt * 16 + col;
                y[o]    = (_Float16)yD[nt][reg];
                base[o] = (_Float16)bD[nt][reg];
            }
        }
    }
}

// ---------------------------------------------------------------------------
// edge: out_i = relu(base_i + max_j y_j). 8 nodes/wave, 8 lanes/node,
// lane covers cols [seg*8, seg*8+8). 16 gathers (16B each) kept in flight,
// packed-f16 max tree, nontemporal on stream-once traffic (src/base/out)
// so y stays L2-resident.
// ---------------------------------------------------------------------------
__global__ __launch_bounds__(256, 4) void edge_max(
    const _Float16* __restrict__ y, const _Float16* __restrict__ base,
    const int* __restrict__ src, float* __restrict__ out,
    int n_groups, int n_nodes)
{
    const int lane = threadIdx.x & 63;
    const int wave = threadIdx.x >> 6;
    int group = blockIdx.x * WPB + wave;
    if (group >= n_groups) group = n_groups - 1;   // dup work, identical writes
    const int nloc = lane >> 3;
    const int seg  = lane & 7;
    int node = group * 8 + nloc;
    if (node >= n_nodes) node = n_nodes - 1;

    // 16 edge sources for this node (8 lanes share -> broadcast loads)
    const i32x4* sp = (const i32x4*)(src + (size_t)node * DEG);
    i32x4 ia = __builtin_nontemporal_load(sp + 0);
    i32x4 ib = __builtin_nontemporal_load(sp + 1);
    i32x4 ic = __builtin_nontemporal_load(sp + 2);
    i32x4 id4 = __builtin_nontemporal_load(sp + 3);
    int id[16] = {ia[0], ia[1], ia[2], ia[3], ib[0], ib[1], ib[2], ib[3],
                  ic[0], ic[1], ic[2], ic[3], id4[0], id4[1], id4[2], id4[3]};

    // gather 16 rows (this lane's 16B slice of each), all in flight
    h8 r[16];
    #pragma unroll
    for (int e = 0; e < 16; ++e)
        r[e] = *(const h8*)(y + (size_t)id[e] * C + seg * 8);

    // packed max tree: 16 -> 1 (llvm.maxnum.v8f16 -> v_pk_max_f16)
    #pragma unroll
    for (int e = 0; e < 8; ++e) r[e] = __builtin_elementwise_max(r[e], r[e + 8]);
    #pragma unroll
    for (int e = 0; e < 4; ++e) r[e] = __builtin_elementwise_max(r[e], r[e + 4]);
    #pragma unroll
    for (int e = 0; e < 2; ++e) r[e] = __builtin_elementwise_max(r[e], r[e + 2]);
    r[0] = __builtin_elementwise_max(r[0], r[1]);

    h8 bs = __builtin_nontemporal_load((const h8*)(base + (size_t)node * C + seg * 8));

    float o[8];
    #pragma unroll
    for (int j = 0; j < 8; ++j)
        o[j] = fmaxf((float)r[0][j] + (float)bs[j], 0.0f);   // relu after max

    float* op = out + (size_t)node * C + seg * 8;
    f32x4 o0 = (f32x4){o[0], o[1], o[2], o[3]};
    f32x4 o1 = (f32x4){o[4], o[5], o[6], o[7]};
    __builtin_nontemporal_store(o0, (f32x4*)op);
    __builtin_nontemporal_store(o1, (f32x4*)op + 1);
}

// ---------------------------------------------------------------------------
// Fallback (no ws): R3-proven kernel, NPW=16, in-wave W build, fp32 gather.
// ---------------------------------------------------------------------------
__global__ __launch_bounds__(256, 2) void edgeconv_fallback(
    const float* __restrict__ x, const int* __restrict__ src,
    const float* __restrict__ W, const float* __restrict__ bias,
    float* __restrict__ out, int n_groups)
{
    const int lane = threadIdx.x & 63, wave = threadIdx.x >> 6;
    const int col = lane & 15, quad = lane >> 4;
    int group = blockIdx.x * WPB + wave;
    if (group >= n_groups) group = n_groups - 1;

    auto frag = [&](int row, int koff) {
        const float* p = x + (size_t)row * C + koff;
        f32x4 a = *(const f32x4*)p, b = *(const f32x4*)(p + 4);
        s16x8 r;
        #pragma unroll
        for (int j = 0; j < 4; ++j) {
            r[j] = (short)f2bf(a[j]); r[j + 4] = (short)f2bf(b[j]);
        }
        return r;
    };

    s16x8 b2[4][2];
    f32x4 baseD[4];
    {
        s16x8 bd[4][2];
        #pragma unroll
        for (int nt = 0; nt < 4; ++nt) {
            const float* wrow = W + (size_t)(nt * 16 + col) * (2 * C);
            #pragma unroll
            for (int ks = 0; ks < 2; ++ks) {
                const int k0 = ks * 32 + quad * 8;
                f32x4 w1a = *(const f32x4*)(wrow + k0);
                f32x4 w1b = *(const f32x4*)(wrow + k0 + 4);
                f32x4 w2a = *(const f32x4*)(wrow + C + k0);
                f32x4 w2b = *(const f32x4*)(wrow + C + k0 + 4);
                s16x8 t2, td;
                #pragma unroll
                for (int j = 0; j < 4; ++j) {
                    t2[j] = (short)f2bf(w2a[j]); t2[j + 4] = (short)f2bf(w2b[j]);
                    td[j] = (short)f2bf(w1a[j] - w2a[j]);
                    td[j + 4] = (short)f2bf(w1b[j] - w2b[j]);
                }
                b2[nt][ks] = t2; bd[nt][ks] = td;
            }
        }
        #pragma unroll
        for (int nt = 0; nt < 4; ++nt) {
            float bv = bias[nt * 16 + col];
            baseD[nt] = (f32x4){bv, bv, bv, bv};
        }
        const int nrow = group * 16 + col;
        s16x8 xi0 = frag(nrow, quad * 8), xi1 = frag(nrow, 32 + quad * 8);
        #pragma unroll
        for (int nt = 0; nt < 4; ++nt) {
            baseD[nt] = __builtin_amdgcn_mfma_f32_16x16x32_bf16(xi0, bd[nt][0], baseD[nt], 0, 0, 0);
            baseD[nt] = __builtin_amdgcn_mfma_f32_16x16x32_bf16(xi1, bd[nt][1], baseD[nt], 0, 0, 0);
        }
    }
    int idx[16];
    #pragma unroll
    for (int n = 0; n < 16; ++n) idx[n] = src[group * 256 + n * DEG + col];
    s16x8 xa[3][2];
    #pragma unroll
    for (int p = 0; p < 2; ++p) {
        xa[p][0] = frag(idx[p], quad * 8); xa[p][1] = frag(idx[p], 32 + quad * 8);
    }
    #pragma unroll
    for (int n = 0; n < 16; ++n) {
        if (n + 2 < 16) {
            xa[(n + 2) % 3][0] = frag(idx[n + 2], quad * 8);
            xa[(n + 2) % 3][1] = frag(idx[n + 2], 32 + quad * 8);
        }
        const int slane = ((n >> 2) << 4) | col;
        f32x4 acc[4];
        #pragma unroll
        for (int nt = 0; nt < 4; ++nt) {
            float bb = __shfl(baseD[nt][n & 3], slane);
            acc[nt] = (f32x4){bb, bb, bb, bb};
        }
        #pragma unroll
        for (int nt = 0; nt < 4; ++nt) {
            acc[nt] = __builtin_amdgcn_mfma_f32_16x16x32_bf16(xa[n % 3][0], b2[nt][0], acc[nt], 0, 0, 0);
            acc[nt] = __builtin_amdgcn_mfma_f32_16x16x32_bf16(xa[n % 3][1], b2[nt][1], acc[nt], 0, 0, 0);
        }
        float m[4];
        #pragma unroll
        for (int nt = 0; nt < 4; ++nt) {
            float t = fmaxf(fmaxf(acc[nt][0], acc[nt][1]),
                            fmaxf(acc[nt][2], acc[nt][3]));
            t = fmaxf(t, __shfl_xor(t, 16));
            t = fmaxf(t, __shfl_xor(t, 32));
            m[nt] = t;
        }
        float r = quad == 0 ? m[0] : quad == 1 ? m[1] : quad == 2 ? m[2] : m[3];
        out[(size_t)(group * 16 + n) * C + lane] = fmaxf(r, 0.0f);
    }
}

extern "C" void kernel_launch(void* const* d_in, const int* in_sizes, int n_in,
                              void* d_out, int out_size, void* d_ws, size_t ws_size,
                              hipStream_t stream) {
    const float* x   = (const float*)d_in[0];
    const int*   src = (const int*)  d_in[1];   // row 0 of edge_index
    const float* W   = (const float*)d_in[3];
    const float* b   = (const float*)d_in[4];
    float*       out = (float*)d_out;

    const int n_nodes = in_sizes[0] / C;                 // 50000
    const size_t need = (size_t)n_nodes * C * 2 * sizeof(_Float16);  // y + base

    if (ws_size >= need) {
        _Float16* y    = (_Float16*)d_ws;
        _Float16* base = y + (size_t)n_nodes * C;
        const int g16 = (n_nodes + 15) / 16;             // 3125 prep groups
        const int g8  = (n_nodes + 7) / 8;               // 6250 edge groups
        prep_gemm<<<(g16 + WPB - 1) / WPB, 256, 0, stream>>>(x, W, b, y, base, g16, n_nodes);
        edge_max<<<(g8 + WPB - 1) / WPB, 256, 0, stream>>>(y, base, src, out, g8, n_nodes);
    } else {
        const int n_groups = (n_nodes + 15) / 16;
        edgeconv_fallback<<<(n_groups + WPB - 1) / WPB, 256, 0, stream>>>(
            x, src, W, b, out, n_groups);
    }
}

// Round 2
// 99.281 us; speedup vs baseline: 1.0535x; 1.0535x over previous
//
#include <hip/hip_runtime.h>

// EdgeConv forward, Round 8: factorized max + register-pressure fixes.
//
// out_i = max_j relu(W@[x_i; x_j-x_i] + b)
//       = relu( base_i + max_{j in N(i)} y_j )        <- relu/+base monotone
// with y_j = x_j @ W2^T (per-NODE) and base_i = b + x_i @ (W1-W2)^T.
//
// prep_gemm: dense 50k x 64 x 64 MFMA pass -> y (fp16), base (fp16) in ws.
//            GPN=2 groups/wave to halve the per-wave W-fragment build cost.
// edge_max:  pure gather kernel. 8 nodes/wave, 8 lanes/node. Gather
//            addresses are 32-bit byte offsets (saddr+voffset form, 1 VGPR
//            each) so all 16 gathers stay in flight under launch_bounds
//            (256,4) without spills (R7 held ~130 VGPR at a 128 cap).
//
// Gather volume is the invariant: 800k x 128B = 102 MB of random 64B-line
// pairs out of a 6.4 MB fp16 y array (cache-served, ~16x reuse). If this
// lands at ~20us the line-request service rate is the ceiling.

#define DEG 16
#define C 64
#define WPB 4    // waves per block
#define GPN 2    // groups per wave in prep_gemm

typedef __attribute__((ext_vector_type(8))) short s16x8;   // 8 bf16
typedef __attribute__((ext_vector_type(4))) float f32x4;
typedef __attribute__((ext_vector_type(4))) int   i32x4;
typedef _Float16 h8 __attribute__((ext_vector_type(8)));   // 8 fp16 = 16B

__device__ __forceinline__ unsigned short f2bf(float f) {
    union { float f; unsigned u; } v; v.f = f;
    unsigned u = v.u + 0x7FFFu + ((v.u >> 16) & 1u);  // round-nearest-even
    return (unsigned short)(u >> 16);
}

// ---------------------------------------------------------------------------
// prep: y[N][64] fp16 = x @ W2^T ;  base[N][64] fp16 = b + x @ (W1-W2)^T
// 16 nodes per group via mfma_f32_16x16x32_bf16 (m89/m91-verified layouts):
//   A[m=lane&15][k=quad*8+j],  B[k][n=lane&15],  D: col=lane&15, row=quad*4+reg
// ---------------------------------------------------------------------------
__global__ __launch_bounds__(256) void prep_gemm(
    const float* __restrict__ x, const float* __restrict__ W,
    const float* __restrict__ bias,
    _Float16* __restrict__ y, _Float16* __restrict__ base,
    int n_groups, int n_nodes)
{
    const int lane = threadIdx.x & 63;
    const int wave = threadIdx.x >> 6;
    const int col  = lane & 15;
    const int quad = lane >> 4;
    const int g0   = (blockIdx.x * WPB + wave) * GPN;

    // W fragments, built once per wave (W is 32KB, L1/L2-hot)
    s16x8 bd[4][2], b2[4][2];
    #pragma unroll
    for (int nt = 0; nt < 4; ++nt) {
        const float* wrow = W + (size_t)(nt * 16 + col) * (2 * C);
        #pragma unroll
        for (int ks = 0; ks < 2; ++ks) {
            const int k0 = ks * 32 + quad * 8;
            f32x4 w1a = *(const f32x4*)(wrow + k0);
            f32x4 w1b = *(const f32x4*)(wrow + k0 + 4);
            f32x4 w2a = *(const f32x4*)(wrow + C + k0);
            f32x4 w2b = *(const f32x4*)(wrow + C + k0 + 4);
            s16x8 t2, td;
            #pragma unroll
            for (int j = 0; j < 4; ++j) {
                t2[j]     = (short)f2bf(w2a[j]);
                t2[j + 4] = (short)f2bf(w2b[j]);
                td[j]     = (short)f2bf(w1a[j] - w2a[j]);
                td[j + 4] = (short)f2bf(w1b[j] - w2b[j]);
            }
            bd[nt][ks] = td;
            b2[nt][ks] = t2;
        }
    }
    float bv[4];
    #pragma unroll
    for (int nt = 0; nt < 4; ++nt) bv[nt] = bias[nt * 16 + col];

    #pragma unroll
    for (int gi = 0; gi < GPN; ++gi) {
        int g = g0 + gi;
        if (g >= n_groups) g = n_groups - 1;   // dup work, identical writes

        int arow = g * 16 + col;
        if (arow >= n_nodes) arow = n_nodes - 1;
        const float* xr = x + (size_t)arow * C;
        f32x4 xa0 = __builtin_nontemporal_load((const f32x4*)(xr + quad * 8));
        f32x4 xa1 = __builtin_nontemporal_load((const f32x4*)(xr + quad * 8 + 4));
        f32x4 xb0 = __builtin_nontemporal_load((const f32x4*)(xr + 32 + quad * 8));
        f32x4 xb1 = __builtin_nontemporal_load((const f32x4*)(xr + 32 + quad * 8 + 4));
        s16x8 xi0, xi1;
        #pragma unroll
        for (int j = 0; j < 4; ++j) {
            xi0[j]     = (short)f2bf(xa0[j]);
            xi0[j + 4] = (short)f2bf(xa1[j]);
            xi1[j]     = (short)f2bf(xb0[j]);
            xi1[j + 4] = (short)f2bf(xb1[j]);
        }

        f32x4 yD[4], bD[4];
        #pragma unroll
        for (int nt = 0; nt < 4; ++nt) {
            bD[nt] = (f32x4){bv[nt], bv[nt], bv[nt], bv[nt]};
            yD[nt] = (f32x4){0.f, 0.f, 0.f, 0.f};
        }
        #pragma unroll
        for (int nt = 0; nt < 4; ++nt) {
            yD[nt] = __builtin_amdgcn_mfma_f32_16x16x32_bf16(xi0, b2[nt][0], yD[nt], 0, 0, 0);
            yD[nt] = __builtin_amdgcn_mfma_f32_16x16x32_bf16(xi1, b2[nt][1], yD[nt], 0, 0, 0);
            bD[nt] = __builtin_amdgcn_mfma_f32_16x16x32_bf16(xi0, bd[nt][0], bD[nt], 0, 0, 0);
            bD[nt] = __builtin_amdgcn_mfma_f32_16x16x32_bf16(xi1, bd[nt][1], bD[nt], 0, 0, 0);
        }

        // fp16 stores; D element (row = quad*4+reg, col = nt*16+col)
        #pragma unroll
        for (int nt = 0; nt < 4; ++nt) {
            #pragma unroll
            for (int reg = 0; reg < 4; ++reg) {
                int orow = g * 16 + quad * 4 + reg;
                if (orow < n_nodes) {
                    size_t o = (size_t)orow * C + nt * 16 + col;
                    y[o]    = (_Float16)yD[nt][reg];
                    base[o] = (_Float16)bD[nt][reg];
                }
            }
        }
    }
}

// ---------------------------------------------------------------------------
// edge: out_i = relu(base_i + max_j y_j). 8 nodes/wave, 8 lanes/node,
// lane covers cols [seg*8, seg*8+8). 16 gathers (16B each, 32-bit voffset)
// kept in flight; packed-f16 max tree; nontemporal on stream-once traffic
// (src/base/out) so y stays cache-resident.
// ---------------------------------------------------------------------------
__global__ __launch_bounds__(256, 4) void edge_max(
    const _Float16* __restrict__ y, const _Float16* __restrict__ base,
    const int* __restrict__ src, float* __restrict__ out,
    int n_groups, int n_nodes)
{
    const int lane = threadIdx.x & 63;
    const int wave = threadIdx.x >> 6;
    int group = blockIdx.x * WPB + wave;
    if (group >= n_groups) group = n_groups - 1;   // dup work, identical writes
    const int nloc = lane >> 3;
    const int seg  = lane & 7;
    int node = group * 8 + nloc;
    if (node >= n_nodes) node = n_nodes - 1;

    // 16 edge sources for this node (8 lanes share -> broadcast loads)
    const i32x4* sp = (const i32x4*)(src + (size_t)node * DEG);
    i32x4 ia  = __builtin_nontemporal_load(sp + 0);
    i32x4 ib  = __builtin_nontemporal_load(sp + 1);
    i32x4 ic  = __builtin_nontemporal_load(sp + 2);
    i32x4 id4 = __builtin_nontemporal_load(sp + 3);

    // 32-bit byte offsets -> saddr + voffset addressing (1 VGPR per addr)
    const unsigned so = (unsigned)(seg << 4);
    unsigned off[16];
    off[0]  = ((unsigned)ia[0]  << 7) + so;  off[1]  = ((unsigned)ia[1]  << 7) + so;
    off[2]  = ((unsigned)ia[2]  << 7) + so;  off[3]  = ((unsigned)ia[3]  << 7) + so;
    off[4]  = ((unsigned)ib[0]  << 7) + so;  off[5]  = ((unsigned)ib[1]  << 7) + so;
    off[6]  = ((unsigned)ib[2]  << 7) + so;  off[7]  = ((unsigned)ib[3]  << 7) + so;
    off[8]  = ((unsigned)ic[0]  << 7) + so;  off[9]  = ((unsigned)ic[1]  << 7) + so;
    off[10] = ((unsigned)ic[2]  << 7) + so;  off[11] = ((unsigned)ic[3]  << 7) + so;
    off[12] = ((unsigned)id4[0] << 7) + so;  off[13] = ((unsigned)id4[1] << 7) + so;
    off[14] = ((unsigned)id4[2] << 7) + so;  off[15] = ((unsigned)id4[3] << 7) + so;

    // gather 16 rows (this lane's 16B slice of each), all in flight
    const char* yb = (const char*)y;
    h8 r[16];
    #pragma unroll
    for (int e = 0; e < 16; ++e)
        r[e] = *(const h8*)(yb + off[e]);

    // packed max tree: 16 -> 1 (llvm.maxnum.v8f16 -> v_pk_max_f16)
    #pragma unroll
    for (int e = 0; e < 8; ++e) r[e] = __builtin_elementwise_max(r[e], r[e + 8]);
    #pragma unroll
    for (int e = 0; e < 4; ++e) r[e] = __builtin_elementwise_max(r[e], r[e + 4]);
    #pragma unroll
    for (int e = 0; e < 2; ++e) r[e] = __builtin_elementwise_max(r[e], r[e + 2]);
    r[0] = __builtin_elementwise_max(r[0], r[1]);

    h8 bs = __builtin_nontemporal_load((const h8*)(base + (size_t)node * C + seg * 8));

    float o[8];
    #pragma unroll
    for (int j = 0; j < 8; ++j)
        o[j] = fmaxf((float)r[0][j] + (float)bs[j], 0.0f);   // relu after max

    float* op = out + (size_t)node * C + seg * 8;
    f32x4 o0 = (f32x4){o[0], o[1], o[2], o[3]};
    f32x4 o1 = (f32x4){o[4], o[5], o[6], o[7]};
    __builtin_nontemporal_store(o0, (f32x4*)op);
    __builtin_nontemporal_store(o1, (f32x4*)op + 1);
}

// ---------------------------------------------------------------------------
// Fallback (no ws): R3-proven kernel, NPW=16, in-wave W build, fp32 gather.
// ---------------------------------------------------------------------------
__global__ __launch_bounds__(256, 2) void edgeconv_fallback(
    const float* __restrict__ x, const int* __restrict__ src,
    const float* __restrict__ W, const float* __restrict__ bias,
    float* __restrict__ out, int n_groups)
{
    const int lane = threadIdx.x & 63, wave = threadIdx.x >> 6;
    const int col = lane & 15, quad = lane >> 4;
    int group = blockIdx.x * WPB + wave;
    if (group >= n_groups) group = n_groups - 1;

    auto frag = [&](int row, int koff) {
        const float* p = x + (size_t)row * C + koff;
        f32x4 a = *(const f32x4*)p, b = *(const f32x4*)(p + 4);
        s16x8 r;
        #pragma unroll
        for (int j = 0; j < 4; ++j) {
            r[j] = (short)f2bf(a[j]); r[j + 4] = (short)f2bf(b[j]);
        }
        return r;
    };

    s16x8 b2[4][2];
    f32x4 baseD[4];
    {
        s16x8 bd[4][2];
        #pragma unroll
        for (int nt = 0; nt < 4; ++nt) {
            const float* wrow = W + (size_t)(nt * 16 + col) * (2 * C);
            #pragma unroll
            for (int ks = 0; ks < 2; ++ks) {
                const int k0 = ks * 32 + quad * 8;
                f32x4 w1a = *(const f32x4*)(wrow + k0);
                f32x4 w1b = *(const f32x4*)(wrow + k0 + 4);
                f32x4 w2a = *(const f32x4*)(wrow + C + k0);
                f32x4 w2b = *(const f32x4*)(wrow + C + k0 + 4);
                s16x8 t2, td;
                #pragma unroll
                for (int j = 0; j < 4; ++j) {
                    t2[j] = (short)f2bf(w2a[j]); t2[j + 4] = (short)f2bf(w2b[j]);
                    td[j] = (short)f2bf(w1a[j] - w2a[j]);
                    td[j + 4] = (short)f2bf(w1b[j] - w2b[j]);
                }
                b2[nt][ks] = t2; bd[nt][ks] = td;
            }
        }
        #pragma unroll
        for (int nt = 0; nt < 4; ++nt) {
            float bv = bias[nt * 16 + col];
            baseD[nt] = (f32x4){bv, bv, bv, bv};
        }
        const int nrow = group * 16 + col;
        s16x8 xi0 = frag(nrow, quad * 8), xi1 = frag(nrow, 32 + quad * 8);
        #pragma unroll
        for (int nt = 0; nt < 4; ++nt) {
            baseD[nt] = __builtin_amdgcn_mfma_f32_16x16x32_bf16(xi0, bd[nt][0], baseD[nt], 0, 0, 0);
            baseD[nt] = __builtin_amdgcn_mfma_f32_16x16x32_bf16(xi1, bd[nt][1], baseD[nt], 0, 0, 0);
        }
    }
    int idx[16];
    #pragma unroll
    for (int n = 0; n < 16; ++n) idx[n] = src[group * 256 + n * DEG + col];
    s16x8 xa[3][2];
    #pragma unroll
    for (int p = 0; p < 2; ++p) {
        xa[p][0] = frag(idx[p], quad * 8); xa[p][1] = frag(idx[p], 32 + quad * 8);
    }
    #pragma unroll
    for (int n = 0; n < 16; ++n) {
        if (n + 2 < 16) {
            xa[(n + 2) % 3][0] = frag(idx[n + 2], quad * 8);
            xa[(n + 2) % 3][1] = frag(idx[n + 2], 32 + quad * 8);
        }
        const int slane = ((n >> 2) << 4) | col;
        f32x4 acc[4];
        #pragma unroll
        for (int nt = 0; nt < 4; ++nt) {
            float bb = __shfl(baseD[nt][n & 3], slane);
            acc[nt] = (f32x4){bb, bb, bb, bb};
        }
        #pragma unroll
        for (int nt = 0; nt < 4; ++nt) {
            acc[nt] = __builtin_amdgcn_mfma_f32_16x16x32_bf16(xa[n % 3][0], b2[nt][0], acc[nt], 0, 0, 0);
            acc[nt] = __builtin_amdgcn_mfma_f32_16x16x32_bf16(xa[n % 3][1], b2[nt][1], acc[nt], 0, 0, 0);
        }
        float m[4];
        #pragma unroll
        for (int nt = 0; nt < 4; ++nt) {
            float t = fmaxf(fmaxf(acc[nt][0], acc[nt][1]),
                            fmaxf(acc[nt][2], acc[nt][3]));
            t = fmaxf(t, __shfl_xor(t, 16));
            t = fmaxf(t, __shfl_xor(t, 32));
            m[nt] = t;
        }
        float r = quad == 0 ? m[0] : quad == 1 ? m[1] : quad == 2 ? m[2] : m[3];
        out[(size_t)(group * 16 + n) * C + lane] = fmaxf(r, 0.0f);
    }
}

extern "C" void kernel_launch(void* const* d_in, const int* in_sizes, int n_in,
                              void* d_out, int out_size, void* d_ws, size_t ws_size,
                              hipStream_t stream) {
    const float* x   = (const float*)d_in[0];
    const int*   src = (const int*)  d_in[1];   // row 0 of edge_index
    const float* W   = (const float*)d_in[3];
    const float* b   = (const float*)d_in[4];
    float*       out = (float*)d_out;

    const int n_nodes = in_sizes[0] / C;                 // 50000
    const size_t need = (size_t)n_nodes * C * 2 * sizeof(_Float16);  // y + base

    if (ws_size >= need) {
        _Float16* y    = (_Float16*)d_ws;
        _Float16* base = y + (size_t)n_nodes * C;
        const int g16 = (n_nodes + 15) / 16;             // 3125 prep groups
        const int nw  = (g16 + GPN - 1) / GPN;           // waves needed
        const int g8  = (n_nodes + 7) / 8;               // 6250 edge groups
        prep_gemm<<<(nw + WPB - 1) / WPB, 256, 0, stream>>>(x, W, b, y, base, g16, n_nodes);
        edge_max<<<(g8 + WPB - 1) / WPB, 256, 0, stream>>>(y, base, src, out, g8, n_nodes);
    } else {
        const int n_groups = (n_nodes + 15) / 16;
        edgeconv_fallback<<<(n_groups + WPB - 1) / WPB, 256, 0, stream>>>(
            x, src, W, b, out, n_groups);
    }
}